// Round 1
// 223.612 us; speedup vs baseline: 1.0011x; 1.0011x over previous
//
#include <hip/hip_runtime.h>

// LIF forward: X [B, T, N] fp32 -> spikes [B, T, N] fp32
// B=128, T=32, N=8192.
//   mem = mem + (x - mem)/2 ; spike = (mem-1 > 0) ; mem = spike ? 0 : mem
// Memory-bound: 268 MB compulsory HBM traffic -> ~42 us floor at 6.4 TB/s.
// R1: float4 naive, VGPR=24, 85.5 us, 2.55 TB/s (loads sunk to uses).
// R2: double-buffer -> compiler collapsed (VGPR 32), neutral.
// R3: float2 full-occupancy TLP -> ~72 us, 2.9 TB/s. TLP insufficient.
// R4: phased loads + sched_barrier -> VGPR=36: loads sunk AGAIN at IR level;
//     sched_barrier only pins the MIR scheduler. 81.5 us.
// R5: asm volatile load burst + single vmcnt(0) + plain stores. Harness
//     dur 223.9 us; rocprof shows kernel < 80 us (hidden under the 512 MiB
//     harness poison fills at ~80 us each), so dur ~= fills + ~63 us kernel.
// R6 (this): chunked counted waits. Single vmcnt(0) serialized the store
//     burst behind the FULL 32-load drain (~900 cy HBM latency for the
//     youngest load with zero overlap). Now: process t in 8 chunks of 4,
//     waiting s_waitcnt vmcnt(28) before each chunk. Accounting is exact
//     and constant: before chunk c, issued = 32 loads + 4c stores; need
//     oldest 4(c+1) loads retired -> N = (32+4c) - 4(c+1) = 28 always.
//     Stores are asm volatile so they are program-order pinned (a sunk
//     store would break the constant-28 arithmetic -> race). Compute+store
//     now overlaps the in-flight tail of the load burst.

#define T_STEPS 32
#define N2 4096           // N/2, compile-time so idx math is shifts
#define TN2 (T_STEPS * N2)
#define CHUNK 4

__global__ __launch_bounds__(256) void lif_fwd_kernel(
    const float2* __restrict__ X, float2* __restrict__ out)
{
    const int idx = blockIdx.x * blockDim.x + threadIdx.x;  // over B * N2
    const int b = idx >> 12;          // / N2
    const int n = idx & (N2 - 1);
    const size_t base = (size_t)b * (size_t)TN2 + (size_t)n;

    const float2* p = X + base;
    float2* po = out + base;

    // ---- Phase A: force-issue ALL 32 timestep loads (volatile asm cannot
    // be sunk by any compiler pass). 64 data VGPRs held live. ----
    float2 x[T_STEPS];
#pragma unroll
    for (int t = 0; t < T_STEPS; ++t) {
        asm volatile("global_load_dwordx2 %0, %1, off"
                     : "=v"(x[t])
                     : "v"(p));
        p += N2;
    }

    // ---- Phase B: chunked scan. Before chunk c: 32 loads + 4c stores
    // issued, need first 4(c+1) loads retired -> vmcnt(28), constant. ----
    float m0 = 0.f, m1 = 0.f;
#pragma unroll
    for (int c = 0; c < T_STEPS / CHUNK; ++c) {
        asm volatile("s_waitcnt vmcnt(28)" ::: "memory");
#pragma unroll
        for (int j = 0; j < CHUNK; ++j) {
            const int t = c * CHUNK + j;
            // Re-tie value AFTER the wait so compute cannot be hoisted
            // above the s_waitcnt.
            asm volatile("" : "+v"(x[t]));

            // exact reference order: mem += (x - mem) * 0.5 ; threshold 1.0
            m0 = m0 + (x[t].x - m0) * 0.5f;
            m1 = m1 + (x[t].y - m1) * 0.5f;

            float2 s;
            s.x = (m0 - 1.0f > 0.0f) ? 1.0f : 0.0f;
            s.y = (m1 - 1.0f > 0.0f) ? 1.0f : 0.0f;

            m0 = (s.x != 0.0f) ? 0.0f : m0;
            m1 = (s.y != 0.0f) ? 0.0f : m1;

            // Volatile store: program-order pinned within the chunk so the
            // vmcnt accounting above stays exact. Fire-and-forget.
            asm volatile("global_store_dwordx2 %0, %1, off"
                         :: "v"(po), "v"(s) : "memory");
            po += N2;
        }
    }
}

extern "C" void kernel_launch(void* const* d_in, const int* in_sizes, int n_in,
                              void* d_out, int out_size, void* d_ws, size_t ws_size,
                              hipStream_t stream) {
    const float2* X = (const float2*)d_in[0];
    float2* out = (float2*)d_out;

    const int total = in_sizes[0];          // B*T*N = 33554432
    const int B = total / (T_STEPS * 8192); // 128
    const int nthreads = B * N2;            // 524288

    const int block = 256;
    const int grid = (nthreads + block - 1) / block;  // 2048

    lif_fwd_kernel<<<grid, block, 0, stream>>>(X, out);
}